// Round 7
// baseline (698.905 us; speedup 1.0000x reference)
//
#include <hip/hip_runtime.h>

#define TS    256
#define ROWS  16
#define DIN   28

typedef _Float16 f16x8 __attribute__((ext_vector_type(8)));
typedef float    f32x4 __attribute__((ext_vector_type(4)));

#if __has_builtin(__builtin_amdgcn_rcpf)
#define RCPF(x) __builtin_amdgcn_rcpf(x)
#else
#define RCPF(x) (1.0f / (x))
#endif
#if __has_builtin(__builtin_amdgcn_exp2f)
#define EXP2F(x) __builtin_amdgcn_exp2f(x)
#else
#define EXP2F(x) exp2f(x)
#endif

// ===== R3's EXACT gate math (last known-good) — no bias-fold, no z4 =====
__device__ __forceinline__ float sigm(float x) {
  return RCPF(1.0f + EXP2F(x * -1.44269504f));
}
__device__ __forceinline__ float tanhf_(float x) {
  return 1.0f - 2.0f * RCPF(1.0f + EXP2F(x * 2.885390082f));
}

__device__ __forceinline__ f16x8 cvt8(float4 a, float4 b) {
  f16x8 r;
  r[0] = (_Float16)a.x; r[1] = (_Float16)a.y; r[2] = (_Float16)a.z; r[3] = (_Float16)a.w;
  r[4] = (_Float16)b.x; r[5] = (_Float16)b.y; r[6] = (_Float16)b.z; r[7] = (_Float16)b.w;
  return r;
}

#define MFMA32(a, b, c) __builtin_amdgcn_mfma_f32_16x16x32_f16((a), (b), (c), 0, 0, 0)

// BISECT: R6's structure (one wave per layer, R2-proven barrier diagonal
// pipeline) + R3's verbatim math (bias broadcast into MFMA C-init, sigm/tanhf_
// helpers). The ONLY remaining delta vs passing-R3 is the one-wave-per-layer
// restructure itself. PASS -> bias-fold was the bug, and we get the solo-perf
// datapoint. FAIL at ~1.97e-2 -> restructure guilty; abandon solo.
__global__ __launch_bounds__(256, 1) void lstm4_diag2(
    const float* __restrict__ x,
    const float* __restrict__ Wih0, const float* __restrict__ Whh0,
    const float* __restrict__ bih0, const float* __restrict__ bhh0,
    const float* __restrict__ Wih1, const float* __restrict__ Whh1,
    const float* __restrict__ bih1, const float* __restrict__ bhh1,
    const float* __restrict__ Wih2, const float* __restrict__ Whh2,
    const float* __restrict__ bih2, const float* __restrict__ bhh2,
    const float* __restrict__ Wih3, const float* __restrict__ Whh3,
    const float* __restrict__ bih3, const float* __restrict__ bhh3,
    const float* __restrict__ Wout, const float* __restrict__ bout,
    float* __restrict__ out)
{
  const int tid  = (int)threadIdx.x;
  const int lane = tid & 63;
  const int l    = tid >> 6;   // wave = layer 0..3
  const int r    = lane & 15;  // A-row (batch row) / B&D-col (h col in tile)
  const int q    = lane >> 4;  // quarter group -> k positions 8q+i (+32kt)
  const int r0   = (int)blockIdx.x * ROWS;

  __shared__ _Float16 hbuf[4][2][ROWS][72] __attribute__((aligned(16)));  // [layer][t&1][row][col]

  for (int i = tid; i < 4 * 2 * ROWS * 72; i += 256)
    (&hbuf[0][0][0][0])[i] = (_Float16)0.0f;
  __syncthreads();

  const float* Wih = (l == 0) ? Wih0 : (l == 1) ? Wih1 : (l == 2) ? Wih2 : Wih3;
  const float* Whh = (l == 0) ? Whh0 : (l == 1) ? Whh1 : (l == 2) ? Whh2 : Whh3;
  const float* bih = (l == 0) ? bih0 : (l == 1) ? bih1 : (l == 2) ? bih2 : bih3;
  const float* bhh = (l == 0) ? bhh0 : (l == 1) ? bhh1 : (l == 2) ? bhh2 : bhh3;

  // B-fragments for the WHOLE layer: [gate][coltile][ktile], k = 32kt+8q+i
  f16x8 wx[4][4][2];
  f16x8 wh[4][4][2];
  float bv[4][4];  // raw bias (R3 style): bih+bhh at this lane's col

#pragma unroll
  for (int g = 0; g < 4; ++g) {
#pragma unroll
    for (int ct = 0; ct < 4; ++ct) {
      const int col = 64 * g + 16 * ct + r;
      if (l == 0) {
        const float* wp = &Wih[col * DIN + 8 * q];
        const float4 a = *(const float4*)wp;
        float4 b = make_float4(0.f, 0.f, 0.f, 0.f);
        if (q < 3) b = *(const float4*)(wp + 4);
        wx[g][ct][0] = cvt8(a, b);
        f16x8 z{}; wx[g][ct][1] = z;
      } else {
        const float* wp = &Wih[col * 64 + 8 * q];
        wx[g][ct][0] = cvt8(*(const float4*)wp, *(const float4*)(wp + 4));
        wx[g][ct][1] = cvt8(*(const float4*)(wp + 32), *(const float4*)(wp + 36));
      }
      const float* hp = &Whh[col * 64 + 8 * q];
      wh[g][ct][0] = cvt8(*(const float4*)hp, *(const float4*)(hp + 4));
      wh[g][ct][1] = cvt8(*(const float4*)(hp + 32), *(const float4*)(hp + 36));
      bv[g][ct] = bih[col] + bhh[col];
    }
  }

  // layer-0 x pipeline: raw float4s loaded one step ahead, converted at use
  const float* xrow = x + (size_t)(r0 + r) * (TS * DIN);
  float4 nx0 = make_float4(0.f, 0.f, 0.f, 0.f), nx1 = nx0;
  if (l == 0) {
    nx0 = *(const float4*)&xrow[8 * q];
    if (q < 3) nx1 = *(const float4*)&xrow[8 * q + 4];
  }

  f32x4 cst[4];
#pragma unroll
  for (int ct = 0; ct < 4; ++ct) cst[ct] = f32x4{0.f, 0.f, 0.f, 0.f};

  for (int s = 0; s < TS + 3; ++s) {
    __syncthreads();                 // one barrier per step, all waves reach it
    const int t = s - l;
    if (t < 0 || t >= TS) continue;  // wave-uniform predicate
    const int sl = t & 1;            // slot this wave writes / reads input from
    const int sp = sl ^ 1;           // slot holding own h_{t-1}

    f16x8 xa{};
    if (l == 0) {
      xa = cvt8(nx0, nx1);           // x_t (loaded last step)
      if (t + 1 < TS) {              // issue x_{t+1} loads now
        const float* xp = &xrow[(t + 1) * DIN + 8 * q];
        nx0 = *(const float4*)xp;
        nx1 = (q < 3) ? *(const float4*)(xp + 4) : make_float4(0.f, 0.f, 0.f, 0.f);
      }
    }

    // A-fragments
    const _Float16* prc = &hbuf[l][sp][r][8 * q];   // own h_{t-1}
    const f16x8 arc0 = *(const f16x8*)prc;
    const f16x8 arc1 = *(const f16x8*)(prc + 32);
    f16x8 ain0{}, ain1{};
    if (l > 0) {
      const _Float16* pin = &hbuf[l - 1][sl][r][8 * q];  // h^{l-1}_t
      ain0 = *(const f16x8*)pin;
      ain1 = *(const f16x8*)(pin + 32);
    }

    // R3-style: bias broadcast into the MFMA C-operand
    f32x4 acc[4][4];
#pragma unroll
    for (int g = 0; g < 4; ++g) {
#pragma unroll
      for (int ct = 0; ct < 4; ++ct) {
        f32x4 a = f32x4{bv[g][ct], bv[g][ct], bv[g][ct], bv[g][ct]};
        if (l == 0) {
          a = MFMA32(xa, wx[g][ct][0], a);
        } else {
          a = MFMA32(ain0, wx[g][ct][0], a);
          a = MFMA32(ain1, wx[g][ct][1], a);
        }
        a = MFMA32(arc0, wh[g][ct][0], a);
        a = MFMA32(arc1, wh[g][ct][1], a);
        acc[g][ct] = a;
      }
    }

    // R3's exact elementwise block (per col tile)
#pragma unroll
    for (int ct = 0; ct < 4; ++ct) {
      _Float16* pw = &hbuf[l][sl][4 * q][16 * ct + r];
#pragma unroll
      for (int j = 0; j < 4; ++j) {
        const float ig = sigm(acc[0][ct][j]);
        const float fg = sigm(acc[1][ct][j]);
        const float gg = tanhf_(acc[2][ct][j]);
        const float og = sigm(acc[3][ct][j]);
        const float c  = fg * cst[ct][j] + ig * gg;
        cst[ct][j] = c;
        pw[j * 72] = (_Float16)(og * tanhf_(c));
      }
    }
  }

  __syncthreads();

  // h3_255 is in slot 255 & 1 = 1; final linear [16 rows] x [10 out]
  if (tid < 160) {
    const int rr = tid & 15;
    const int oc = tid >> 4;
    float a = bout[oc];
#pragma unroll 16
    for (int k = 0; k < 64; ++k)
      a += (float)hbuf[3][1][rr][k] * Wout[oc * 64 + k];
    out[(size_t)(r0 + rr) * 10 + oc] = a;
  }
}

extern "C" void kernel_launch(void* const* d_in, const int* in_sizes, int n_in,
                              void* d_out, int out_size, void* d_ws, size_t ws_size,
                              hipStream_t stream) {
  (void)in_sizes; (void)n_in; (void)d_ws; (void)ws_size; (void)out_size;
  lstm4_diag2<<<dim3(4096 / ROWS), dim3(256), 0, stream>>>(
      (const float*)d_in[0],
      (const float*)d_in[1],  (const float*)d_in[2],  (const float*)d_in[3],  (const float*)d_in[4],
      (const float*)d_in[5],  (const float*)d_in[6],  (const float*)d_in[7],  (const float*)d_in[8],
      (const float*)d_in[9],  (const float*)d_in[10], (const float*)d_in[11], (const float*)d_in[12],
      (const float*)d_in[13], (const float*)d_in[14], (const float*)d_in[15], (const float*)d_in[16],
      (const float*)d_in[17], (const float*)d_in[18],
      (float*)d_out);
}

// Round 8
// 614.435 us; speedup vs baseline: 1.1375x; 1.1375x over previous
//
#include <hip/hip_runtime.h>

#define TS    256
#define ROWS  16
#define DIN   28

typedef _Float16 f16x8 __attribute__((ext_vector_type(8)));
typedef _Float16 f16x4 __attribute__((ext_vector_type(4)));
typedef float    f32x4 __attribute__((ext_vector_type(4)));

#if __has_builtin(__builtin_amdgcn_rcpf)
#define RCPF(x) __builtin_amdgcn_rcpf(x)
#else
#define RCPF(x) (1.0f / (x))
#endif
#if __has_builtin(__builtin_amdgcn_exp2f)
#define EXP2F(x) __builtin_amdgcn_exp2f(x)
#else
#define EXP2F(x) exp2f(x)
#endif

// ===== FROZEN gate math (R3/R7 proven; do not fold biases/scales) =====
__device__ __forceinline__ float sigm(float x) {
  return RCPF(1.0f + EXP2F(x * -1.44269504f));
}
__device__ __forceinline__ float tanhf_(float x) {
  return 1.0f - 2.0f * RCPF(1.0f + EXP2F(x * 2.885390082f));
}

__device__ __forceinline__ f16x8 cvt8(float4 a, float4 b) {
  f16x8 r;
  r[0] = (_Float16)a.x; r[1] = (_Float16)a.y; r[2] = (_Float16)a.z; r[3] = (_Float16)a.w;
  r[4] = (_Float16)b.x; r[5] = (_Float16)b.y; r[6] = (_Float16)b.z; r[7] = (_Float16)b.w;
  return r;
}

#define MFMA32(a, b, c) __builtin_amdgcn_mfma_f32_16x16x32_f16((a), (b), (c), 0, 0, 0)

// R2 geometry (4 layers x 4 col-waves, 16-wave block, barrier diagonal) with
// OPERAND-SWAPPED MFMA: D = W-frag x h-frag -> lane holds (h-col 4q+j, row r),
// so h-writes are one packed ds_write_b64 (was 4 scattered b16 -> bank
// conflicts). Fragments are byte-identical to the proven ones; only the
// intrinsic's operand order changes. Bias becomes per-reg f32x4, staged in LDS
// (protects the <=128 VGPR/wave budget a 16-wave block requires). Gate
// nonlinearities interleaved with MFMA chains in source order to de-phase
// trans vs MFMA pipes.
__global__ __launch_bounds__(1024, 4) void lstm4_swap(
    const float* __restrict__ x,
    const float* __restrict__ Wih0, const float* __restrict__ Whh0,
    const float* __restrict__ bih0, const float* __restrict__ bhh0,
    const float* __restrict__ Wih1, const float* __restrict__ Whh1,
    const float* __restrict__ bih1, const float* __restrict__ bhh1,
    const float* __restrict__ Wih2, const float* __restrict__ Whh2,
    const float* __restrict__ bih2, const float* __restrict__ bhh2,
    const float* __restrict__ Wih3, const float* __restrict__ Whh3,
    const float* __restrict__ bih3, const float* __restrict__ bhh3,
    const float* __restrict__ Wout, const float* __restrict__ bout,
    float* __restrict__ out)
{
  const int tid  = (int)threadIdx.x;
  const int lane = tid & 63;
  const int w    = tid >> 6;   // wave 0..15
  const int l    = w >> 2;     // layer 0..3 (SIMD i hosts one wave of each layer)
  const int wv   = w & 3;      // col tile -> h cols [16wv, 16wv+16)
  const int r    = lane & 15;  // batch row (B-frag col / D col)
  const int q    = lane >> 4;  // quarter group -> k = 8q+i; D rows 4q+j
  const int r0   = (int)blockIdx.x * ROWS;

  __shared__ _Float16 hbuf[4][2][ROWS][72] __attribute__((aligned(16)));
  __shared__ float bsum[4][256];  // bih+bhh per layer (keeps per-reg bias out of VGPRs)

  for (int i = tid; i < 4 * 2 * ROWS * 72; i += 1024)
    (&hbuf[0][0][0][0])[i] = (_Float16)0.0f;
  {
    const float* bihA[4] = {bih0, bih1, bih2, bih3};
    const float* bhhA[4] = {bhh0, bhh1, bhh2, bhh3};
    const int ll = tid >> 8, cc = tid & 255;   // 1024 threads cover 4x256
    bsum[ll][cc] = bihA[ll][cc] + bhhA[ll][cc];
  }
  __syncthreads();

  const float* Wih = (l == 0) ? Wih0 : (l == 1) ? Wih1 : (l == 2) ? Wih2 : Wih3;
  const float* Whh = (l == 0) ? Whh0 : (l == 1) ? Whh1 : (l == 2) ? Whh2 : Whh3;

  // Weight fragments (identical packing to proven kernels; now the A-operand):
  // lane (q,r) holds W[64g + 16wv + r][32kt + 8q + i]
  f16x8 wxf[4][2];
  f16x8 whf[4][2];
#pragma unroll
  for (int g = 0; g < 4; ++g) {
    const int col = 64 * g + 16 * wv + r;
    if (l == 0) {
      const float* wp = &Wih[col * DIN + 8 * q];
      const float4 a = *(const float4*)wp;
      float4 b = make_float4(0.f, 0.f, 0.f, 0.f);
      if (q < 3) b = *(const float4*)(wp + 4);
      wxf[g][0] = cvt8(a, b);
      f16x8 z{}; wxf[g][1] = z;   // unused on l=0 path (DCE'd)
    } else {
#pragma unroll
      for (int kt = 0; kt < 2; ++kt)
        wxf[g][kt] = cvt8(*(const float4*)&Wih[col * 64 + kt * 32 + 8 * q],
                          *(const float4*)&Wih[col * 64 + kt * 32 + 8 * q + 4]);
    }
#pragma unroll
    for (int kt = 0; kt < 2; ++kt)
      whf[g][kt] = cvt8(*(const float4*)&Whh[col * 64 + kt * 32 + 8 * q],
                        *(const float4*)&Whh[col * 64 + kt * 32 + 8 * q + 4]);
  }

  // layer-0 x pipeline (B-operand now; same packing): x[r0+r][t][8q+i]
  const float* xrow = x + (size_t)(r0 + r) * (TS * DIN);
  float4 nx0 = make_float4(0.f, 0.f, 0.f, 0.f), nx1 = nx0;
  if (l == 0) {
    nx0 = *(const float4*)&xrow[8 * q];
    if (q < 3) nx1 = *(const float4*)&xrow[8 * q + 4];
  }

  // this lane owns h elements (row r, col 16wv + 4q + j), j=0..3
  f32x4 cst = f32x4{0.f, 0.f, 0.f, 0.f};
  const float* bb = &bsum[l][16 * wv + 4 * q];

  for (int s = 0; s < TS + 3; ++s) {
    __syncthreads();                 // one barrier per step (proven protocol)
    const int t = s - l;
    if (t < 0 || t >= TS) continue;  // wave-uniform predicate
    const int sl = t & 1;
    const int sp = sl ^ 1;

    f16x8 xa{};
    if (l == 0) {
      xa = cvt8(nx0, nx1);
      if (t + 1 < TS) {
        const float* xp = &xrow[(t + 1) * DIN + 8 * q];
        nx0 = *(const float4*)xp;
        nx1 = (q < 3) ? *(const float4*)(xp + 4) : make_float4(0.f, 0.f, 0.f, 0.f);
      }
    }

    // B-operand fragments from LDS (same reads as proven kernels)
    const _Float16* prc = &hbuf[l][sp][r][8 * q];   // own h_{t-1}
    const f16x8 arc0 = *(const f16x8*)prc;
    const f16x8 arc1 = *(const f16x8*)(prc + 32);
    f16x8 ain0{}, ain1{};
    if (l > 0) {
      const _Float16* pin = &hbuf[l - 1][sl][r][8 * q];  // h^{l-1}_t
      ain0 = *(const f16x8*)pin;
      ain1 = *(const f16x8*)(pin + 32);
    }

    // per-reg bias vectors (f32x4 from LDS; short-lived registers)
    const f32x4 bv0 = *(const f32x4*)(bb + 0);
    const f32x4 bv1 = *(const f32x4*)(bb + 64);
    const f32x4 bv2 = *(const f32x4*)(bb + 128);
    const f32x4 bv3 = *(const f32x4*)(bb + 192);

    // Swapped-operand MFMA chains, interleaved with gate nonlinearities so the
    // trans pipe fills while later gates' MFMAs are still in flight.
    f32x4 a0, a1, a2, a3, igv, fgv, ggv, ogv;
    if (l == 0) {
      a0 = MFMA32(wxf[0][0], xa, bv0);
      a0 = MFMA32(whf[0][0], arc0, a0);
      a0 = MFMA32(whf[0][1], arc1, a0);
      a1 = MFMA32(wxf[1][0], xa, bv1);
      a1 = MFMA32(whf[1][0], arc0, a1);
      a1 = MFMA32(whf[1][1], arc1, a1);
#pragma unroll
      for (int j = 0; j < 4; ++j) igv[j] = sigm(a0[j]);
      a2 = MFMA32(wxf[2][0], xa, bv2);
      a2 = MFMA32(whf[2][0], arc0, a2);
      a2 = MFMA32(whf[2][1], arc1, a2);
#pragma unroll
      for (int j = 0; j < 4; ++j) fgv[j] = sigm(a1[j]);
      a3 = MFMA32(wxf[3][0], xa, bv3);
      a3 = MFMA32(whf[3][0], arc0, a3);
      a3 = MFMA32(whf[3][1], arc1, a3);
    } else {
      a0 = MFMA32(wxf[0][0], ain0, bv0);
      a0 = MFMA32(wxf[0][1], ain1, a0);
      a0 = MFMA32(whf[0][0], arc0, a0);
      a0 = MFMA32(whf[0][1], arc1, a0);
      a1 = MFMA32(wxf[1][0], ain0, bv1);
      a1 = MFMA32(wxf[1][1], ain1, a1);
      a1 = MFMA32(whf[1][0], arc0, a1);
      a1 = MFMA32(whf[1][1], arc1, a1);
#pragma unroll
      for (int j = 0; j < 4; ++j) igv[j] = sigm(a0[j]);
      a2 = MFMA32(wxf[2][0], ain0, bv2);
      a2 = MFMA32(wxf[2][1], ain1, a2);
      a2 = MFMA32(whf[2][0], arc0, a2);
      a2 = MFMA32(whf[2][1], arc1, a2);
#pragma unroll
      for (int j = 0; j < 4; ++j) fgv[j] = sigm(a1[j]);
      a3 = MFMA32(wxf[3][0], ain0, bv3);
      a3 = MFMA32(wxf[3][1], ain1, a3);
      a3 = MFMA32(whf[3][0], arc0, a3);
      a3 = MFMA32(whf[3][1], arc1, a3);
    }
#pragma unroll
    for (int j = 0; j < 4; ++j) ggv[j] = tanhf_(a2[j]);
#pragma unroll
    for (int j = 0; j < 4; ++j) ogv[j] = sigm(a3[j]);

    // c/h update + ONE packed b64 write of 4 consecutive h cols
    f16x4 hv;
#pragma unroll
    for (int j = 0; j < 4; ++j) {
      const float c = fgv[j] * cst[j] + igv[j] * ggv[j];
      cst[j] = c;
      hv[j] = (_Float16)(ogv[j] * tanhf_(c));
    }
    *(f16x4*)&hbuf[l][sl][r][16 * wv + 4 * q] = hv;
  }

  __syncthreads();

  // h3_255 is in slot 255 & 1 = 1; final linear [16 rows] x [10 out]
  if (tid < 160) {
    const int rr = tid & 15;
    const int oc = tid >> 4;
    float a = bout[oc];
#pragma unroll 16
    for (int k = 0; k < 64; ++k)
      a += (float)hbuf[3][1][rr][k] * Wout[oc * 64 + k];
    out[(size_t)(r0 + rr) * 10 + oc] = a;
  }
}

extern "C" void kernel_launch(void* const* d_in, const int* in_sizes, int n_in,
                              void* d_out, int out_size, void* d_ws, size_t ws_size,
                              hipStream_t stream) {
  (void)in_sizes; (void)n_in; (void)d_ws; (void)ws_size; (void)out_size;
  lstm4_swap<<<dim3(4096 / ROWS), dim3(1024), 0, stream>>>(
      (const float*)d_in[0],
      (const float*)d_in[1],  (const float*)d_in[2],  (const float*)d_in[3],  (const float*)d_in[4],
      (const float*)d_in[5],  (const float*)d_in[6],  (const float*)d_in[7],  (const float*)d_in[8],
      (const float*)d_in[9],  (const float*)d_in[10], (const float*)d_in[11], (const float*)d_in[12],
      (const float*)d_in[13], (const float*)d_in[14], (const float*)d_in[15], (const float*)d_in[16],
      (const float*)d_in[17], (const float*)d_in[18],
      (float*)d_out);
}